// Round 10
// baseline (177.039 us; speedup 1.0000x reference)
//
#include <hip/hip_runtime.h>
#include <hip/hip_bf16.h>
#include <stdint.h>

#define M_DIM 4096
#define N_DIM 4096
#define K_DIM 4096
#define NH 128
#define NW 128
#define NKT 64   // K-tiles of BK=64

typedef short bf16x8 __attribute__((ext_vector_type(8)));
typedef short bf16x4 __attribute__((ext_vector_type(4)));
typedef float f32x4 __attribute__((ext_vector_type(4)));

#define MFMA(a, b, c) __builtin_amdgcn_mfma_f32_16x16x32_bf16((a), (b), (c), 0, 0, 0)

__device__ __forceinline__ short f2bf(float f) {
  union { float f; unsigned u; } c; c.f = f;
  unsigned u = c.u;
  unsigned r = (u + 0x7fffu + ((u >> 16) & 1u)) >> 16;  // RNE
  return (short)r;
}

// ---------------- kernel 1: per-32x32-block mask ----------------
__global__ __launch_bounds__(256) void k_block_mask(const int* __restrict__ mask,
                                                    const float* __restrict__ conv_bias,
                                                    int* __restrict__ bm) {
  const int bw = blockIdx.x, bh = blockIdx.y;
  const int t = threadIdx.x;
  const int row = t >> 3;
  const int c4 = (t & 7) << 2;
  const int4* p = (const int4*)(mask + (size_t)(bh * 32 + row) * K_DIM + bw * 32 + c4);
  int4 v = *p;
  int s = v.x + v.y + v.z + v.w;
#pragma unroll
  for (int off = 32; off > 0; off >>= 1) s += __shfl_down(s, off);
  __shared__ int red[4];
  if ((t & 63) == 0) red[t >> 6] = s;
  __syncthreads();
  if (t == 0) {
    float tot = (float)(red[0] + red[1] + red[2] + red[3]) + conv_bias[0];
    bm[bh * NW + bw] = (tot > 0.0f) ? 1 : 0;
  }
}

// ---------------- kernel 2: data f32 -> bf16 ----------------
__global__ __launch_bounds__(256) void k_cvt_data(const float* __restrict__ in,
                                                  short* __restrict__ ob) {
  size_t i = (size_t)blockIdx.x * 256 + threadIdx.x;
  f32x4 v = ((const f32x4*)in)[i];
  bf16x4 o;
  o[0] = f2bf(v[0]); o[1] = f2bf(v[1]); o[2] = f2bf(v[2]); o[3] = f2bf(v[3]);
  ((bf16x4*)ob)[i] = o;
}

// ---------------- kernel 3: weight f32 -> masked bf16 ----------------
__global__ __launch_bounds__(256) void k_cvt_weight(const float* __restrict__ w,
                                                    const int* __restrict__ bm,
                                                    short* __restrict__ ob) {
  size_t i = (size_t)blockIdx.x * 256 + threadIdx.x;
  int n = (int)(i >> 10);
  int k = ((int)i & 1023) << 2;
  float m = bm[((n >> 5) << 7) + (k >> 5)] ? 1.0f : 0.0f;
  f32x4 v = ((const f32x4*)w)[i];
  bf16x4 o;
  o[0] = f2bf(v[0] * m); o[1] = f2bf(v[1] * m);
  o[2] = f2bf(v[2] * m); o[3] = f2bf(v[3] * m);
  ((bf16x4*)ob)[i] = o;
}

// ---------------- kernel 4: 256x256 1-barrier-per-tile bf16 NT GEMM --------
// 8 waves M-split (32 rows each, acc[2][16]); WG-uniform block gates.
// TRUE double-buffer: tile u stages ALL of tile u+1 (A+B, 8 glls) into buf^1
// at tile START; single VMW(0)+s_barrier at tile END (glls are ~1 tile old by
// then). All in-tile ds_reads consumed by in-tile MFMAs before the barrier
// (A-reads gated by anyC/anyD so no unconsumed read crosses the barrier).
// In-tile register pipeline R0,R1,C0,R2,C1,R3,C2,C3 (lgkmcnt counted by
// compiler overlaps reads under MFMA clusters).
__global__ __launch_bounds__(512, 2) void k_gemm256(const short* __restrict__ Ab,
                                                    const short* __restrict__ Bb,
                                                    const float* __restrict__ bias,
                                                    const int* __restrict__ bm,
                                                    float* __restrict__ out) {
  __shared__ short Asm[2][2][256][32];  // [buf][ks][row][colseg*8] 64 KB
  __shared__ short Bsm[2][2][256][32];  // 64 KB

  const int tid = threadIdx.x;
  const int wid = tid >> 6, lane = tid & 63;
  const int r = lane & 15, g0 = lane >> 4;
  const int gs = g0 ^ ((r >> 1) & 3);      // swizzled col-seg for ds_read

  // XCD-aware swizzle: 256 wgs, 8 XCDs, 32/XCD (bijective since 256%8==0)
  const int swz = (blockIdx.x & 7) * 32 + (blockIdx.x >> 3);
  const int bx = swz & 15, by = swz >> 4;
  const int rowM = by * 256, colN = bx * 256;

  // staging geometry: 512 thr x 16B = one (h,ks) 8KB region, linear LDS dest
  const int srow = tid >> 2;                         // 0..127 within half
  const int sseg = (tid & 3) ^ ((tid >> 3) & 3);     // pre-swizzled source seg
  const int swave = wid * 512;                       // wave-uniform LDS base (shorts)

  const short* gA = Ab + (size_t)(rowM + srow) * K_DIM + sseg * 8;
  const short* gB = Bb + (size_t)(colN + srow) * K_DIM + sseg * 8;
  const size_t HOFF = (size_t)128 * K_DIM;

  // ---- WG-uniform mask bits: 8 n-block rows x 128 k-blocks -> 16x u64 ----
  const int* bp = bm + (size_t)(colN >> 5) * NW;
  unsigned long long m0l = __ballot(bp[0 * 128 + lane] != 0);
  unsigned long long m0h = __ballot(bp[0 * 128 + 64 + lane] != 0);
  unsigned long long m1l = __ballot(bp[1 * 128 + lane] != 0);
  unsigned long long m1h = __ballot(bp[1 * 128 + 64 + lane] != 0);
  unsigned long long m2l = __ballot(bp[2 * 128 + lane] != 0);
  unsigned long long m2h = __ballot(bp[2 * 128 + 64 + lane] != 0);
  unsigned long long m3l = __ballot(bp[3 * 128 + lane] != 0);
  unsigned long long m3h = __ballot(bp[3 * 128 + 64 + lane] != 0);
  unsigned long long m4l = __ballot(bp[4 * 128 + lane] != 0);
  unsigned long long m4h = __ballot(bp[4 * 128 + 64 + lane] != 0);
  unsigned long long m5l = __ballot(bp[5 * 128 + lane] != 0);
  unsigned long long m5h = __ballot(bp[5 * 128 + 64 + lane] != 0);
  unsigned long long m6l = __ballot(bp[6 * 128 + lane] != 0);
  unsigned long long m6h = __ballot(bp[6 * 128 + 64 + lane] != 0);
  unsigned long long m7l = __ballot(bp[7 * 128 + lane] != 0);
  unsigned long long m7h = __ballot(bp[7 * 128 + 64 + lane] != 0);
  __builtin_amdgcn_sched_barrier(0);  // mask loads fully retired before staging

#define BTJ(J, kc) ((int)((((kc) & 64) ? m##J##h : m##J##l) >> ((kc) & 63)) & 1)

#define GLL(g, l)                                                            \
  __builtin_amdgcn_global_load_lds((const __attribute__((address_space(1))) void*)(g), \
                                   (__attribute__((address_space(3))) void*)(l), 16, 0, 0)
#define STA(BUF, kt, h, ks) GLL(gA + HOFF * (h) + (size_t)(kt) * 64 + (ks) * 32, \
                                &Asm[BUF][ks][(h) * 128][0] + swave)
#define STB(BUF, kt, h, ks) GLL(gB + HOFF * (h) + (size_t)(kt) * 64 + (ks) * 32, \
                                &Bsm[BUF][ks][(h) * 128][0] + swave)

#define LDA(BUF, ks, m) (*(const bf16x8*)&Asm[BUF][ks][wid * 32 + (m) * 16 + r][gs * 8])
#define LDB(BUF, ks, n) (*(const bf16x8*)&Bsm[BUF][ks][(n) * 16 + r][gs * 8])

// 4 MFMAs of one (j-block, ks): frag cols f, f+1
#define MFJ(A0, A1, B0, B1, f)                                               \
  acc[0][f] = MFMA(A0, B0, acc[0][f]);   acc[1][f] = MFMA(A1, B0, acc[1][f]); \
  acc[0][(f) + 1] = MFMA(A0, B1, acc[0][(f) + 1]);                           \
  acc[1][(f) + 1] = MFMA(A1, B1, acc[1][(f) + 1]);

#define BAR __builtin_amdgcn_s_barrier()
#define SB0 __builtin_amdgcn_sched_barrier(0)
#define PRIO1 __builtin_amdgcn_s_setprio(1)
#define PRIO0 __builtin_amdgcn_s_setprio(0)
#define VMW0 asm volatile("s_waitcnt vmcnt(0)" ::: "memory")

// One K-tile: stages first (deepest in flight), then the in-tile read/MFMA
// pipeline, then VMW0+BAR. SG gates staging (off for last tile). All gates
// WG-uniform scalar branches; every issued ds_read has an in-tile consumer.
#define TILE(BUF, NB, u, SG)                                                 \
  {                                                                          \
    const int kb = 2 * (u);                                                  \
    const int c0 = BTJ(0, kb), c1 = BTJ(1, kb), c2 = BTJ(2, kb), c3 = BTJ(3, kb); \
    const int c4 = BTJ(4, kb), c5 = BTJ(5, kb), c6 = BTJ(6, kb), c7 = BTJ(7, kb); \
    const int d0 = BTJ(0, kb + 1), d1 = BTJ(1, kb + 1), d2 = BTJ(2, kb + 1), d3 = BTJ(3, kb + 1); \
    const int d4 = BTJ(4, kb + 1), d5 = BTJ(5, kb + 1), d6 = BTJ(6, kb + 1), d7 = BTJ(7, kb + 1); \
    const int anyC = c0 | c1 | c2 | c3 | c4 | c5 | c6 | c7;                  \
    const int anyD = d0 | d1 | d2 | d3 | d4 | d5 | d6 | d7;                  \
    if (SG) {                                                                \
      STA(NB, (u) + 1, 0, 0); STA(NB, (u) + 1, 1, 0);                        \
      STA(NB, (u) + 1, 0, 1); STA(NB, (u) + 1, 1, 1);                        \
      STB(NB, (u) + 1, 0, 0); STB(NB, (u) + 1, 1, 0);                        \
      STB(NB, (u) + 1, 0, 1); STB(NB, (u) + 1, 1, 1);                        \
    }                                                                        \
    /* R0: A ks0 + B ks0 j0-3 */                                             \
    if (anyC) { aX0 = LDA(BUF, 0, 0); aX1 = LDA(BUF, 0, 1); }                \
    if (c0) { bA[0] = LDB(BUF, 0, 0); bA[1] = LDB(BUF, 0, 1); }              \
    if (c1) { bA[2] = LDB(BUF, 0, 2); bA[3] = LDB(BUF, 0, 3); }              \
    if (c2) { bA[4] = LDB(BUF, 0, 4); bA[5] = LDB(BUF, 0, 5); }              \
    if (c3) { bA[6] = LDB(BUF, 0, 6); bA[7] = LDB(BUF, 0, 7); }              \
    /* R1: B ks0 j4-7 */                                                     \
    if (c4) { bB[0] = LDB(BUF, 0, 8);  bB[1] = LDB(BUF, 0, 9); }             \
    if (c5) { bB[2] = LDB(BUF, 0, 10); bB[3] = LDB(BUF, 0, 11); }            \
    if (c6) { bB[4] = LDB(BUF, 0, 12); bB[5] = LDB(BUF, 0, 13); }            \
    if (c7) { bB[6] = LDB(BUF, 0, 14); bB[7] = LDB(BUF, 0, 15); }            \
    /* C0: ks0 j0-3 */                                                       \
    PRIO1;                                                                   \
    if (c0) { MFJ(aX0, aX1, bA[0], bA[1], 0) }                               \
    if (c1) { MFJ(aX0, aX1, bA[2], bA[3], 2) }                               \
    if (c2) { MFJ(aX0, aX1, bA[4], bA[5], 4) }                               \
    if (c3) { MFJ(aX0, aX1, bA[6], bA[7], 6) }                               \
    PRIO0;                                                                   \
    /* R2: A ks1 + B ks1 j0-3 */                                             \
    if (anyD) { aY0 = LDA(BUF, 1, 0); aY1 = LDA(BUF, 1, 1); }                \
    if (d0) { bA[0] = LDB(BUF, 1, 0); bA[1] = LDB(BUF, 1, 1); }              \
    if (d1) { bA[2] = LDB(BUF, 1, 2); bA[3] = LDB(BUF, 1, 3); }              \
    if (d2) { bA[4] = LDB(BUF, 1, 4); bA[5] = LDB(BUF, 1, 5); }              \
    if (d3) { bA[6] = LDB(BUF, 1, 6); bA[7] = LDB(BUF, 1, 7); }              \
    /* C1: ks0 j4-7 */                                                       \
    PRIO1;                                                                   \
    if (c4) { MFJ(aX0, aX1, bB[0], bB[1], 8) }                               \
    if (c5) { MFJ(aX0, aX1, bB[2], bB[3], 10) }                              \
    if (c6) { MFJ(aX0, aX1, bB[4], bB[5], 12) }                              \
    if (c7) { MFJ(aX0, aX1, bB[6], bB[7], 14) }                              \
    PRIO0;                                                                   \
    /* R3: B ks1 j4-7 */                                                     \
    if (d4) { bB[0] = LDB(BUF, 1, 8);  bB[1] = LDB(BUF, 1, 9); }             \
    if (d5) { bB[2] = LDB(BUF, 1, 10); bB[3] = LDB(BUF, 1, 11); }            \
    if (d6) { bB[4] = LDB(BUF, 1, 12); bB[5] = LDB(BUF, 1, 13); }            \
    if (d7) { bB[6] = LDB(BUF, 1, 14); bB[7] = LDB(BUF, 1, 15); }            \
    /* C2: ks1 j0-3 */                                                       \
    PRIO1;                                                                   \
    if (d0) { MFJ(aY0, aY1, bA[0], bA[1], 0) }                               \
    if (d1) { MFJ(aY0, aY1, bA[2], bA[3], 2) }                               \
    if (d2) { MFJ(aY0, aY1, bA[4], bA[5], 4) }                               \
    if (d3) { MFJ(aY0, aY1, bA[6], bA[7], 6) }                               \
    /* C3: ks1 j4-7 */                                                       \
    if (d4) { MFJ(aY0, aY1, bB[0], bB[1], 8) }                               \
    if (d5) { MFJ(aY0, aY1, bB[2], bB[3], 10) }                              \
    if (d6) { MFJ(aY0, aY1, bB[4], bB[5], 12) }                              \
    if (d7) { MFJ(aY0, aY1, bB[6], bB[7], 14) }                              \
    PRIO0;                                                                   \
    VMW0; BAR; SB0;                                                          \
  }

  f32x4 acc[2][16];
#pragma unroll
  for (int m = 0; m < 2; ++m)
#pragma unroll
    for (int n = 0; n < 16; ++n) acc[m][n] = (f32x4){0.f, 0.f, 0.f, 0.f};

  bf16x8 aX0, aX1, aY0, aY1, bA[8], bB[8];

  // prologue: stage tile 0 fully into buf0, drain, barrier.
  STA(0, 0, 0, 0); STA(0, 0, 1, 0); STA(0, 0, 0, 1); STA(0, 0, 1, 1);
  STB(0, 0, 0, 0); STB(0, 0, 1, 0); STB(0, 0, 0, 1); STB(0, 0, 1, 1);
  VMW0;
  BAR; SB0;

#pragma unroll 1
  for (int u = 0; u < NKT - 2; u += 2) {
    TILE(0, 1, u, 1);
    TILE(1, 0, u + 1, 1);
  }
  TILE(0, 1, NKT - 2, 1);   // stages tile 63
  TILE(1, 0, NKT - 1, 0);   // last tile, no staging

  // epilogue: C/D layout col=lane&15 (=r), row=(lane>>4)*4+j (=g0*4+j)
  const int orow = rowM + wid * 32;
#pragma unroll
  for (int n = 0; n < 16; ++n) {
    int col = colN + n * 16 + r;
    float bz = bias[col];
#pragma unroll
    for (int m = 0; m < 2; ++m) {
      int row0 = orow + m * 16 + g0 * 4;
#pragma unroll
      for (int j = 0; j < 4; ++j)
        out[(size_t)(row0 + j) * N_DIM + col] = acc[m][n][j] + bz;
    }
  }
#undef TILE
#undef GLL
#undef STA
#undef STB
#undef LDA
#undef LDB
#undef MFJ
#undef BAR
#undef SB0
#undef PRIO1
#undef PRIO0
#undef VMW0
#undef BTJ
}

// ---------------- fallback (ws too small): naive fp32 ----------------
__global__ __launch_bounds__(256) void k_naive(const float* __restrict__ A,
                                               const float* __restrict__ W,
                                               const float* __restrict__ bias,
                                               const int* __restrict__ bm,
                                               float* __restrict__ out) {
  int col = blockIdx.x * 16 + (threadIdx.x & 15);
  int row = blockIdx.y * 16 + (threadIdx.x >> 4);
  float s = 0.f;
  for (int kb = 0; kb < K_DIM / 32; ++kb) {
    if (bm[(col >> 5) * NW + kb]) {
      int kbase = kb * 32;
#pragma unroll 8
      for (int k = 0; k < 32; ++k)
        s += A[(size_t)row * K_DIM + kbase + k] * W[(size_t)col * K_DIM + kbase + k];
    }
  }
  out[(size_t)row * N_DIM + col] = s + bias[col];
}

extern "C" void kernel_launch(void* const* d_in, const int* in_sizes, int n_in,
                              void* d_out, int out_size, void* d_ws, size_t ws_size,
                              hipStream_t stream) {
  const float* data = (const float*)d_in[0];
  const float* weight = (const float*)d_in[1];
  const float* bias = (const float*)d_in[2];
  const int* mask = (const int*)d_in[3];
  const float* conv_bias = (const float*)d_in[4];
  float* out = (float*)d_out;

  int* bm = (int*)d_ws;
  const size_t off_a = 65536;
  const size_t off_b = off_a + (size_t)M_DIM * K_DIM * 2;
  const size_t needed = off_b + (size_t)N_DIM * K_DIM * 2;

  k_block_mask<<<dim3(NW, NH), 256, 0, stream>>>(mask, conv_bias, bm);

  if (ws_size >= needed) {
    short* Abf = (short*)((char*)d_ws + off_a);
    short* Wbf = (short*)((char*)d_ws + off_b);
    k_cvt_data<<<dim3((M_DIM * (K_DIM / 4)) / 256), 256, 0, stream>>>(data, Abf);
    k_cvt_weight<<<dim3((N_DIM * (K_DIM / 4)) / 256), 256, 0, stream>>>(weight, bm, Wbf);
    k_gemm256<<<dim3(256), 512, 0, stream>>>(Abf, Wbf, bias, bm, out);
  } else {
    k_naive<<<dim3(N_DIM / 16, M_DIM / 16), 256, 0, stream>>>(data, weight, bias, bm, out);
  }
}

// Round 11
// 142.856 us; speedup vs baseline: 1.2393x; 1.2393x over previous
//
#include <hip/hip_runtime.h>
#include <hip/hip_bf16.h>
#include <stdint.h>

#define M_DIM 4096
#define N_DIM 4096
#define K_DIM 4096
#define NH 128
#define NW 128
#define NKT 64   // K-tiles of BK=64

typedef short bf16x8 __attribute__((ext_vector_type(8)));
typedef short bf16x4 __attribute__((ext_vector_type(4)));
typedef float f32x4 __attribute__((ext_vector_type(4)));

#define MFMA(a, b, c) __builtin_amdgcn_mfma_f32_16x16x32_bf16((a), (b), (c), 0, 0, 0)

__device__ __forceinline__ short f2bf(float f) {
  union { float f; unsigned u; } c; c.f = f;
  unsigned u = c.u;
  unsigned r = (u + 0x7fffu + ((u >> 16) & 1u)) >> 16;  // RNE
  return (short)r;
}

// ------- kernel 1: fused per-block mask + masked weight f32->bf16 ----------
// One WG per 32x32 weight block. Reduce mask block -> activity; write bm;
// active: read+convert weight block; inactive: write zeros WITHOUT reading
// weight (block-uniform branch, saves ~32 MB of reads at ~50% sparsity).
__global__ __launch_bounds__(256) void k_mask_weight(const int* __restrict__ mask,
                                                     const float* __restrict__ conv_bias,
                                                     const float* __restrict__ w,
                                                     int* __restrict__ bm,
                                                     short* __restrict__ ob) {
  const int bw = blockIdx.x, bh = blockIdx.y;   // bw = k-block, bh = n-block
  const int t = threadIdx.x;
  const int row = t >> 3;          // 32 rows, 8 threads/row
  const int c4 = (t & 7) << 2;     // 4 elems each
  const size_t off = (size_t)(bh * 32 + row) * K_DIM + bw * 32 + c4;

  int4 v = *(const int4*)(mask + off);
  int s = v.x + v.y + v.z + v.w;
#pragma unroll
  for (int o = 32; o > 0; o >>= 1) s += __shfl_down(s, o);
  __shared__ int red[4];
  __shared__ int active;
  if ((t & 63) == 0) red[t >> 6] = s;
  __syncthreads();
  if (t == 0) {
    float tot = (float)(red[0] + red[1] + red[2] + red[3]) + conv_bias[0];
    int a = (tot > 0.0f) ? 1 : 0;
    bm[bh * NW + bw] = a;
    active = a;
  }
  __syncthreads();

  bf16x4 o;
  if (active) {
    f32x4 wv = *(const f32x4*)(w + off);
    o[0] = f2bf(wv[0]); o[1] = f2bf(wv[1]); o[2] = f2bf(wv[2]); o[3] = f2bf(wv[3]);
  } else {
    o[0] = 0; o[1] = 0; o[2] = 0; o[3] = 0;
  }
  *(bf16x4*)(ob + off) = o;
}

// ---------------- kernel 2: data f32 -> bf16 ----------------
__global__ __launch_bounds__(256) void k_cvt_data(const float* __restrict__ in,
                                                  short* __restrict__ ob) {
  size_t i = (size_t)blockIdx.x * 256 + threadIdx.x;
  f32x4 v = ((const f32x4*)in)[i];
  bf16x4 o;
  o[0] = f2bf(v[0]); o[1] = f2bf(v[1]); o[2] = f2bf(v[2]); o[3] = f2bf(v[3]);
  ((bf16x4*)ob)[i] = o;
}

// ---------------- kernel 4: 256x256 4-phase, M-split waves, uniform gates ---
// (byte-exact round-9 GEMM: read-ahead pipeline, stage slots, vmcnt 6/4,
// XOR+XCD swizzle; 8 waves x 32 M-rows, acc[2][16]; WG-uniform block gates.)
__global__ __launch_bounds__(512, 2) void k_gemm256(const short* __restrict__ Ab,
                                                    const short* __restrict__ Bb,
                                                    const float* __restrict__ bias,
                                                    const int* __restrict__ bm,
                                                    float* __restrict__ out) {
  __shared__ short Asm[2][2][256][32];  // [buf][ks][row][colseg*8] 64 KB
  __shared__ short Bsm[2][2][256][32];  // 64 KB

  const int tid = threadIdx.x;
  const int wid = tid >> 6, lane = tid & 63;
  const int r = lane & 15, g0 = lane >> 4;
  const int gs = g0 ^ ((r >> 1) & 3);      // swizzled col-seg for ds_read

  // XCD-aware swizzle: 256 wgs, 8 XCDs, 32/XCD (bijective since 256%8==0)
  const int swz = (blockIdx.x & 7) * 32 + (blockIdx.x >> 3);
  const int bx = swz & 15, by = swz >> 4;
  const int rowM = by * 256, colN = bx * 256;

  // staging geometry: 512 thr x 16B = one (h,ks) 8KB region, linear LDS dest
  const int srow = tid >> 2;                         // 0..127 within half
  const int sseg = (tid & 3) ^ ((tid >> 3) & 3);     // pre-swizzled source seg
  const int swave = wid * 512;                       // wave-uniform LDS base (shorts)

  const short* gA = Ab + (size_t)(rowM + srow) * K_DIM + sseg * 8;
  const short* gB = Bb + (size_t)(colN + srow) * K_DIM + sseg * 8;
  const size_t HOFF = (size_t)128 * K_DIM;

  // ---- WG-uniform mask bits: 8 n-block rows x 128 k-blocks -> 16x u64 ----
  const int* bp = bm + (size_t)(colN >> 5) * NW;
  unsigned long long m0l = __ballot(bp[0 * 128 + lane] != 0);
  unsigned long long m0h = __ballot(bp[0 * 128 + 64 + lane] != 0);
  unsigned long long m1l = __ballot(bp[1 * 128 + lane] != 0);
  unsigned long long m1h = __ballot(bp[1 * 128 + 64 + lane] != 0);
  unsigned long long m2l = __ballot(bp[2 * 128 + lane] != 0);
  unsigned long long m2h = __ballot(bp[2 * 128 + 64 + lane] != 0);
  unsigned long long m3l = __ballot(bp[3 * 128 + lane] != 0);
  unsigned long long m3h = __ballot(bp[3 * 128 + 64 + lane] != 0);
  unsigned long long m4l = __ballot(bp[4 * 128 + lane] != 0);
  unsigned long long m4h = __ballot(bp[4 * 128 + 64 + lane] != 0);
  unsigned long long m5l = __ballot(bp[5 * 128 + lane] != 0);
  unsigned long long m5h = __ballot(bp[5 * 128 + 64 + lane] != 0);
  unsigned long long m6l = __ballot(bp[6 * 128 + lane] != 0);
  unsigned long long m6h = __ballot(bp[6 * 128 + 64 + lane] != 0);
  unsigned long long m7l = __ballot(bp[7 * 128 + lane] != 0);
  unsigned long long m7h = __ballot(bp[7 * 128 + 64 + lane] != 0);
  __builtin_amdgcn_sched_barrier(0);  // mask loads fully retired before staging

#define BTJ(J, kc) ((int)((((kc) & 64) ? m##J##h : m##J##l) >> ((kc) & 63)) & 1)

#define GLL(g, l)                                                            \
  __builtin_amdgcn_global_load_lds((const __attribute__((address_space(1))) void*)(g), \
                                   (__attribute__((address_space(3))) void*)(l), 16, 0, 0)
#define STA(BUF, kt, h, ks) GLL(gA + HOFF * (h) + (size_t)(kt) * 64 + (ks) * 32, \
                                &Asm[BUF][ks][(h) * 128][0] + swave)
#define STB(BUF, kt, h, ks) GLL(gB + HOFF * (h) + (size_t)(kt) * 64 + (ks) * 32, \
                                &Bsm[BUF][ks][(h) * 128][0] + swave)

#define LDA(BUF, ks, m) (*(const bf16x8*)&Asm[BUF][ks][wid * 32 + (m) * 16 + r][gs * 8])
#define LDB(BUF, ks, n) (*(const bf16x8*)&Bsm[BUF][ks][(n) * 16 + r][gs * 8])

// 4 MFMAs of one (j-block, ks): frag cols f, f+1
#define MFJ(A0, A1, B0, B1, f)                                               \
  acc[0][f] = MFMA(A0, B0, acc[0][f]);   acc[1][f] = MFMA(A1, B0, acc[1][f]); \
  acc[0][(f) + 1] = MFMA(A0, B1, acc[0][(f) + 1]);                           \
  acc[1][(f) + 1] = MFMA(A1, B1, acc[1][(f) + 1]);

#define BAR __builtin_amdgcn_s_barrier()
#define SB0 __builtin_amdgcn_sched_barrier(0)
#define PRIO1 __builtin_amdgcn_s_setprio(1)
#define PRIO0 __builtin_amdgcn_s_setprio(0)
#define VMW_(N) asm volatile("s_waitcnt vmcnt(" #N ")" ::: "memory")
#define VMW(N) VMW_(N)

#define TILE(BUF, NB, u, SB, SA, SR, VM0, VM2)                               \
  {                                                                          \
    const int kb = 2 * (u);                                                  \
    const int c0 = BTJ(0, kb), c1 = BTJ(1, kb), c2 = BTJ(2, kb), c3 = BTJ(3, kb); \
    const int c4 = BTJ(4, kb), c5 = BTJ(5, kb), c6 = BTJ(6, kb), c7 = BTJ(7, kb); \
    const int d0 = BTJ(0, kb + 1), d1 = BTJ(1, kb + 1), d2 = BTJ(2, kb + 1), d3 = BTJ(3, kb + 1); \
    const int d4 = BTJ(4, kb + 1), d5 = BTJ(5, kb + 1), d6 = BTJ(6, kb + 1), d7 = BTJ(7, kb + 1); \
    /* P0: MFMA ks0 j0-3 (bA); read A ks1 + B ks0 j4-7 -> bB */              \
    BAR; SB0;                                                                \
    aY0 = LDA(BUF, 1, 0); aY1 = LDA(BUF, 1, 1);                              \
    if (c4) { bB[0] = LDB(BUF, 0, 8);  bB[1] = LDB(BUF, 0, 9); }             \
    if (c5) { bB[2] = LDB(BUF, 0, 10); bB[3] = LDB(BUF, 0, 11); }            \
    if (c6) { bB[4] = LDB(BUF, 0, 12); bB[5] = LDB(BUF, 0, 13); }            \
    if (c7) { bB[6] = LDB(BUF, 0, 14); bB[7] = LDB(BUF, 0, 15); }            \
    PRIO1;                                                                   \
    if (c0) { MFJ(aX0, aX1, bA[0], bA[1], 0) }                               \
    if (c1) { MFJ(aX0, aX1, bA[2], bA[3], 2) }                               \
    if (c2) { MFJ(aX0, aX1, bA[4], bA[5], 4) }                               \
    if (c3) { MFJ(aX0, aX1, bA[6], bA[7], 6) }                               \
    PRIO0;                                                                   \
    if (SB) { STB(NB, (u) + 1, 0, 0); STB(NB, (u) + 1, 1, 0); }              \
    VMW(VM0);                                                                \
    /* P1: MFMA ks0 j4-7 (bB); read B ks1 j0-3 -> bA */                      \
    BAR; SB0;                                                                \
    if (d0) { bA[0] = LDB(BUF, 1, 0); bA[1] = LDB(BUF, 1, 1); }              \
    if (d1) { bA[2] = LDB(BUF, 1, 2); bA[3] = LDB(BUF, 1, 3); }              \
    if (d2) { bA[4] = LDB(BUF, 1, 4); bA[5] = LDB(BUF, 1, 5); }              \
    if (d3) { bA[6] = LDB(BUF, 1, 6); bA[7] = LDB(BUF, 1, 7); }              \
    PRIO1;                                                                   \
    if (c4) { MFJ(aX0, aX1, bB[0], bB[1], 8) }                               \
    if (c5) { MFJ(aX0, aX1, bB[2], bB[3], 10) }                              \
    if (c6) { MFJ(aX0, aX1, bB[4], bB[5], 12) }                              \
    if (c7) { MFJ(aX0, aX1, bB[6], bB[7], 14) }                              \
    PRIO0;                                                                   \
    if (SB) { STB(NB, (u) + 1, 0, 1); STB(NB, (u) + 1, 1, 1); }              \
    /* P2: MFMA ks1 j0-3 (bA); read B ks1 j4-7 -> bB */                      \
    BAR; SB0;                                                                \
    if (d4) { bB[0] = LDB(BUF, 1, 8);  bB[1] = LDB(BUF, 1, 9); }             \
    if (d5) { bB[2] = LDB(BUF, 1, 10); bB[3] = LDB(BUF, 1, 11); }            \
    if (d6) { bB[4] = LDB(BUF, 1, 12); bB[5] = LDB(BUF, 1, 13); }            \
    if (d7) { bB[6] = LDB(BUF, 1, 14); bB[7] = LDB(BUF, 1, 15); }            \
    PRIO1;                                                                   \
    if (d0) { MFJ(aY0, aY1, bA[0], bA[1], 0) }                               \
    if (d1) { MFJ(aY0, aY1, bA[2], bA[3], 2) }                               \
    if (d2) { MFJ(aY0, aY1, bA[4], bA[5], 4) }                               \
    if (d3) { MFJ(aY0, aY1, bA[6], bA[7], 6) }                               \
    PRIO0;                                                                   \
    if (SA) { STA(BUF, (u) + 2, 0, 0); STA(BUF, (u) + 2, 1, 0); }            \
    VMW(VM2);                                                                \
    /* P3: MFMA ks1 j4-7 (bB); cross-tile read A ks0 + B ks0 j0-3 -> bA */   \
    BAR; SB0;                                                                \
    if (SR) {                                                                \
      const int n0 = BTJ(0, kb + 2), n1 = BTJ(1, kb + 2);                    \
      const int n2 = BTJ(2, kb + 2), n3 = BTJ(3, kb + 2);                    \
      aX0 = LDA(NB, 0, 0); aX1 = LDA(NB, 0, 1);                              \
      if (n0) { bA[0] = LDB(NB, 0, 0); bA[1] = LDB(NB, 0, 1); }              \
      if (n1) { bA[2] = LDB(NB, 0, 2); bA[3] = LDB(NB, 0, 3); }              \
      if (n2) { bA[4] = LDB(NB, 0, 4); bA[5] = LDB(NB, 0, 5); }              \
      if (n3) { bA[6] = LDB(NB, 0, 6); bA[7] = LDB(NB, 0, 7); }              \
    }                                                                        \
    PRIO1;                                                                   \
    if (d4) { MFJ(aY0, aY1, bB[0], bB[1], 8) }                               \
    if (d5) { MFJ(aY0, aY1, bB[2], bB[3], 10) }                              \
    if (d6) { MFJ(aY0, aY1, bB[4], bB[5], 12) }                              \
    if (d7) { MFJ(aY0, aY1, bB[6], bB[7], 14) }                              \
    PRIO0;                                                                   \
    if (SA) { STA(BUF, (u) + 2, 0, 1); STA(BUF, (u) + 2, 1, 1); }            \
  }

  f32x4 acc[2][16];
#pragma unroll
  for (int m = 0; m < 2; ++m)
#pragma unroll
    for (int n = 0; n < 16; ++n) acc[m][n] = (f32x4){0.f, 0.f, 0.f, 0.f};

  bf16x8 aX0, aX1, aY0, aY1, bA[8], bB[8];

  // prologue stages (round-6 FIFO): [A0 x4, B0 x4 | A1 x4]; vmcnt(4) -> A0,B0.
  STA(0, 0, 0, 0); STA(0, 0, 1, 0); STA(0, 0, 0, 1); STA(0, 0, 1, 1);
  STB(0, 0, 0, 0); STB(0, 0, 1, 0); STB(0, 0, 0, 1); STB(0, 0, 1, 1);
  STA(1, 1, 0, 0); STA(1, 1, 1, 0); STA(1, 1, 0, 1); STA(1, 1, 1, 1);
  VMW(4);
  BAR; SB0;
  // preload tile-0 P0 operands (gated by tile-0 ks0 j0-3 bits)
  {
    const int p0 = BTJ(0, 0), p1 = BTJ(1, 0), p2 = BTJ(2, 0), p3 = BTJ(3, 0);
    aX0 = LDA(0, 0, 0); aX1 = LDA(0, 0, 1);
    if (p0) { bA[0] = LDB(0, 0, 0); bA[1] = LDB(0, 0, 1); }
    if (p1) { bA[2] = LDB(0, 0, 2); bA[3] = LDB(0, 0, 3); }
    if (p2) { bA[4] = LDB(0, 0, 4); bA[5] = LDB(0, 0, 5); }
    if (p3) { bA[6] = LDB(0, 0, 6); bA[7] = LDB(0, 0, 7); }
  }

#pragma unroll 1
  for (int u = 0; u < NKT - 2; u += 2) {
    TILE(0, 1, u, 1, 1, 1, 6, 4);
    TILE(1, 0, u + 1, 1, 1, 1, 6, 4);
  }
  // peeled tails (round-6 counts): tile 62 stages B63 only; tile 63 no stages.
  TILE(0, 1, NKT - 2, 1, 0, 1, 6, 2);
  TILE(1, 0, NKT - 1, 0, 0, 0, 0, 0);

  // epilogue: C/D layout col=lane&15 (=r), row=(lane>>4)*4+j (=g0*4+j)
  const int orow = rowM + wid * 32;
#pragma unroll
  for (int n = 0; n < 16; ++n) {
    int col = colN + n * 16 + r;
    float bz = bias[col];
#pragma unroll
    for (int m = 0; m < 2; ++m) {
      int row0 = orow + m * 16 + g0 * 4;
#pragma unroll
      for (int j = 0; j < 4; ++j)
        out[(size_t)(row0 + j) * N_DIM + col] = acc[m][n][j] + bz;
    }
  }
#undef TILE
#undef GLL
#undef STA
#undef STB
#undef LDA
#undef LDB
#undef MFJ
#undef BAR
#undef SB0
#undef PRIO1
#undef PRIO0
#undef VMW
#undef VMW_
#undef BTJ
}

// ---------------- fallback (ws too small): naive fp32 ----------------
__global__ __launch_bounds__(256) void k_naive(const float* __restrict__ A,
                                               const float* __restrict__ W,
                                               const float* __restrict__ bias,
                                               const int* __restrict__ bm,
                                               float* __restrict__ out) {
  int col = blockIdx.x * 16 + (threadIdx.x & 15);
  int row = blockIdx.y * 16 + (threadIdx.x >> 4);
  float s = 0.f;
  for (int kb = 0; kb < K_DIM / 32; ++kb) {
    if (bm[(col >> 5) * NW + kb]) {
      int kbase = kb * 32;
#pragma unroll 8
      for (int k = 0; k < 32; ++k)
        s += A[(size_t)row * K_DIM + kbase + k] * W[(size_t)col * K_DIM + kbase + k];
    }
  }
  out[(size_t)row * N_DIM + col] = s + bias[col];
}

// block-mask only (fallback path needs bm without weight conversion)
__global__ __launch_bounds__(256) void k_block_mask(const int* __restrict__ mask,
                                                    const float* __restrict__ conv_bias,
                                                    int* __restrict__ bm) {
  const int bw = blockIdx.x, bh = blockIdx.y;
  const int t = threadIdx.x;
  const int row = t >> 3;
  const int c4 = (t & 7) << 2;
  const int4* p = (const int4*)(mask + (size_t)(bh * 32 + row) * K_DIM + bw * 32 + c4);
  int4 v = *p;
  int s = v.x + v.y + v.z + v.w;
#pragma unroll
  for (int off = 32; off > 0; off >>= 1) s += __shfl_down(s, off);
  __shared__ int red[4];
  if ((t & 63) == 0) red[t >> 6] = s;
  __syncthreads();
  if (t == 0) {
    float tot = (float)(red[0] + red[1] + red[2] + red[3]) + conv_bias[0];
    bm[bh * NW + bw] = (tot > 0.0f) ? 1 : 0;
  }
}

extern "C" void kernel_launch(void* const* d_in, const int* in_sizes, int n_in,
                              void* d_out, int out_size, void* d_ws, size_t ws_size,
                              hipStream_t stream) {
  const float* data = (const float*)d_in[0];
  const float* weight = (const float*)d_in[1];
  const float* bias = (const float*)d_in[2];
  const int* mask = (const int*)d_in[3];
  const float* conv_bias = (const float*)d_in[4];
  float* out = (float*)d_out;

  int* bm = (int*)d_ws;
  const size_t off_a = 65536;
  const size_t off_b = off_a + (size_t)M_DIM * K_DIM * 2;
  const size_t needed = off_b + (size_t)N_DIM * K_DIM * 2;

  if (ws_size >= needed) {
    short* Abf = (short*)((char*)d_ws + off_a);
    short* Wbf = (short*)((char*)d_ws + off_b);
    k_mask_weight<<<dim3(NW, NH), 256, 0, stream>>>(mask, conv_bias, weight, bm, Wbf);
    k_cvt_data<<<dim3((M_DIM * (K_DIM / 4)) / 256), 256, 0, stream>>>(data, Abf);
    k_gemm256<<<dim3(256), 512, 0, stream>>>(Abf, Wbf, bias, bm, out);
  } else {
    k_block_mask<<<dim3(NW, NH), 256, 0, stream>>>(mask, conv_bias, bm);
    k_naive<<<dim3(N_DIM / 16, M_DIM / 16), 256, 0, stream>>>(data, weight, bias, bm, out);
  }
}